// Round 5
// baseline (314.409 us; speedup 1.0000x reference)
//
#include <hip/hip_runtime.h>
#include <hip/hip_bf16.h>
#include <string.h>

typedef unsigned short u16;
typedef unsigned int   u32;
using short8  = __attribute__((ext_vector_type(8))) short;
using float4v = __attribute__((ext_vector_type(4))) float;

#define DEV static __device__ __forceinline__

DEV u16 f2bf(float f) {
  union { float f; u32 u; } v; v.f = f;
  u32 u = v.u;
  return (u16)((u + 0x7fffu + ((u >> 16) & 1u)) >> 16);   // RNE
}
DEV float bf2f(u16 b) {
  union { u32 u; float f; } v; v.u = ((u32)b) << 16;
  return v.f;
}
DEV void gload16(const void* g, void* lds) {
  __builtin_amdgcn_global_load_lds((const __attribute__((address_space(1))) void*)g,
                                   (__attribute__((address_space(3))) void*)lds, 16, 0, 0);
}
DEV float4v mfma16(short8 a, short8 b, float4v c) {
  return __builtin_amdgcn_mfma_f32_16x16x32_bf16(a, b, c, 0, 0, 0);
}

// ---------------- problem constants ----------------
#define SCALE_F 0.07216878364870323f        // (3*64)^-0.5
#define KSQS_F  0.10412730065142986f        // SCALE * log2(e)
#define C2_F    0.20825460130285973f        // 2 * SCALE * log2(e)
#define THR_F   11.541560327111707f         // 8 * log2(e)

// ---------------- workspace layout (byte offsets) ----------------
#define OFF_XH   0ull
#define OFF_XL   6291456ull
#define OFF_AO1  0ull                        // aliases X (dead after qkv_gemm)
#define OFF_WH   12582912ull
#define OFF_WL   13369344ull
#define OFF_WOH  14155776ull
#define OFF_QKVH 14417920ull
#define OFF_QKVL 39583744ull
#define OFF_VT   64749568ull
#define OFF_KSQ  77332480ull                 // f32 [16][2048] pre-scaled

// ================= kernel 1: split inputs into bf16 hi/lo =================
__global__ __launch_bounds__(256) void prep_kernel(
    const float* __restrict__ x, const float* __restrict__ wq,
    const float* __restrict__ wkv, const float* __restrict__ wout,
    u16* __restrict__ XH, u16* __restrict__ XL,
    u16* __restrict__ WH, u16* __restrict__ WL, u16* __restrict__ WOH) {
  int t = blockIdx.x * 256 + threadIdx.x;
  if (t < 1048576) {                       // per (bn,i): coalesced float3 read
    const float* xp = x + t * 3;
    float f0 = xp[0], f1 = xp[1], f2 = xp[2];
#pragma unroll
    for (int c = 0; c < 3; ++c) {
      float f = (c == 0) ? f0 : (c == 1 ? f1 : f2);
      u16 h = f2bf(f);
      XH[c * 1048576 + t] = h;
      XL[c * 1048576 + t] = f2bf(f - bf2f(h));
    }
  } else if (t < 1048576 + 393216) {       // w_q / w_kv rows, K contiguous
    int wi = t - 1048576;
    int o = wi >> 8, i = wi & 255;
    float f = (o < 512) ? wq[o * 256 + i] : wkv[(o - 512) * 256 + i];
    u16 h = f2bf(f);
    WH[wi] = h;
    WL[wi] = f2bf(f - bf2f(h));
  } else if (t < 1048576 + 393216 + 131072) {
    int wi = t - 1048576 - 393216;
    WOH[wi] = f2bf(wout[wi]);
  }
}

// ================= kernel 2: QKV projection GEMM (bf16x2) =================
__global__ __launch_bounds__(256) void qkv_gemm(
    const u16* __restrict__ XH, const u16* __restrict__ XL,
    const u16* __restrict__ WH, const u16* __restrict__ WL,
    u16* __restrict__ QKVH, u16* __restrict__ QKVL, u16* __restrict__ VT) {
  __shared__ u16 smem[16384];
  int m0 = blockIdx.x * 128;
  int n0 = blockIdx.y * 128;
  bool isV = (n0 >= 1024);
  int tid = threadIdx.x, lane = tid & 63, wave = tid >> 6;
  int la = lane & 15, qa = lane >> 4;
  int wm = wave >> 1, wn = wave & 1;

  float4v acc[4][4];
#pragma unroll
  for (int i = 0; i < 4; ++i)
#pragma unroll
    for (int j = 0; j < 4; ++j) acc[i][j] = (float4v){0.f, 0.f, 0.f, 0.f};

  for (int k0 = 0; k0 < 256; k0 += 32) {
    __syncthreads();
#pragma unroll
    for (int it = 0; it < 8; ++it) {
      int cb = it * 256 + wave * 64;
      int n = cb + lane;
      int region = n >> 9;
      if (isV && (region & 1)) continue;
      int nn = n & 511;
      int row = nn >> 2, p = nn & 3;
      int q = p ^ ((row >> 1) & 3);
      const u16* src;
      if (region == 0)      src = XH + (m0 + row) * 256 + k0 + q * 8;
      else if (region == 1) src = XL + (m0 + row) * 256 + k0 + q * 8;
      else if (region == 2) src = WH + (n0 + row) * 256 + k0 + q * 8;
      else                  src = WL + (n0 + row) * 256 + k0 + q * 8;
      gload16(src, smem + cb * 8);
    }
    __syncthreads();

    short8 ah[4], al[4];
#pragma unroll
    for (int mi = 0; mi < 4; ++mi) {
      int row = wm * 64 + mi * 16 + la;
      int off = row * 32 + ((qa ^ ((row >> 1) & 3)) * 8);
      ah[mi] = *(const short8*)(smem + off);
      if (!isV) al[mi] = *(const short8*)(smem + 4096 + off);
    }
#pragma unroll
    for (int ni = 0; ni < 4; ++ni) {
      int row = wn * 64 + ni * 16 + la;
      int off = row * 32 + ((qa ^ ((row >> 1) & 3)) * 8);
      short8 bh = *(const short8*)(smem + 8192 + off);
      if (!isV) {
        short8 bl = *(const short8*)(smem + 12288 + off);
#pragma unroll
        for (int mi = 0; mi < 4; ++mi) {
          acc[mi][ni] = mfma16(ah[mi], bh, acc[mi][ni]);
          acc[mi][ni] = mfma16(ah[mi], bl, acc[mi][ni]);
          acc[mi][ni] = mfma16(al[mi], bh, acc[mi][ni]);
        }
      } else {
#pragma unroll
        for (int mi = 0; mi < 4; ++mi) acc[mi][ni] = mfma16(ah[mi], bh, acc[mi][ni]);
      }
    }
  }

#pragma unroll
  for (int mi = 0; mi < 4; ++mi)
#pragma unroll
    for (int ni = 0; ni < 4; ++ni) {
      int n = n0 + wn * 64 + ni * 16 + la;
      int mbase = m0 + wm * 64 + mi * 16 + qa * 4;
#pragma unroll
      for (int r = 0; r < 4; ++r) {
        int m = mbase + r;
        float v = acc[mi][ni][r];
        if (!isV) {
          u16 h = f2bf(v);
          QKVH[m * 1024 + n] = h;
          QKVL[m * 1024 + n] = f2bf(v - bf2f(h));
        } else {
          int c = m >> 12, bn = m & 4095;
          int bb = bn >> 11, j = bn & 2047;
          int hd = n - 1024;
          int hh = hd >> 6, d = hd & 63;
          VT[((bb * 8 + hh) * 192 + (c * 64 + d)) * 2048 + j] = f2bf(v);
        }
      }
    }
}

// ================= kernel 3: KSQ2[bh][j] = (sum k^2) * SCALE*log2e =========
__global__ __launch_bounds__(512) void ksq_kernel(
    const u16* __restrict__ QKVH, const u16* __restrict__ QKVL, float* __restrict__ KSQ2) {
  int bn = blockIdx.x;
  int t = threadIdx.x;
  float s = 0.f;
#pragma unroll
  for (int c = 0; c < 3; ++c) {
    int off = (c * 4096 + bn) * 1024 + 512 + t;
    float v = bf2f(QKVH[off]) + bf2f(QKVL[off]);
    s += v * v;
  }
#pragma unroll
  for (int o = 1; o < 64; o <<= 1) s += __shfl_xor(s, o);
  if ((t & 63) == 0) {
    int h = t >> 6;
    int b = bn >> 11, j = bn & 2047;
    KSQ2[(b * 8 + h) * 2048 + j] = s * KSQS_F;
  }
}

// ================= kernel 4: flash attention, KVB=64, m x j wave split ====
// grid 512 (16 bh x 32 qb), 8 waves = 4 m-tiles x 2 j-halves, QB=64, dbuf.
// LDS u16: buf{Kh[64][192]@0, Kl@12288, V[192][64]@24576} x2 (BUFU=36864),
// P @73728 (8x512) -> 155648 B total (1 block/CU). Each K/V LDS byte now
// serves 64 j-cols (m-duplication 4x not 8x) -> LDS traffic per j halved.
__global__ __launch_bounds__(512) void attn_kernel(
    const u16* __restrict__ QKVH, const u16* __restrict__ QKVL,
    const u16* __restrict__ VT, const float* __restrict__ KSQ2,
    u16* __restrict__ AO) {
  __shared__ u16 smem[77824];
  const int BUFU = 36864;
  int wgid = blockIdx.x;
  int xcd = wgid & 7, sl = wgid >> 3;           // 64 slots per XCD
  int bh = xcd * 2 + (sl & 1);                  // XCD owns bh pair -> L2-resident K/V
  int qb = sl >> 1;                             // 0..31
  int b = bh >> 3, h = bh & 7;
  int tid = threadIdx.x, wave = tid >> 6, lane = tid & 63;
  int la = lane & 15, qa = lane >> 4;
  int wm = wave >> 1, wj = wave & 1;

  // Q fragments in registers (16 rows per wave)
  short8 qh[6], ql[6];
  int irow = qb * 64 + wm * 16 + la;
#pragma unroll
  for (int kk = 0; kk < 6; ++kk) {
    int kap = kk * 32 + qa * 8;
    int c = kap >> 6, d0 = kap & 63;
    int off = (c * 4096 + b * 2048 + irow) * 1024 + h * 64 + d0;
    qh[kk] = *(const short8*)(QKVH + off);
    ql[kk] = *(const short8*)(QKVL + off);
  }
  float4v O[12];
#pragma unroll
  for (int i = 0; i < 12; ++i) O[i] = (float4v){0.f, 0.f, 0.f, 0.f};
  float mr[4] = {-1e30f, -1e30f, -1e30f, -1e30f};
  float ssum[4] = {0.f, 0.f, 0.f, 0.f};          // lane-partial; reduced at epilogue
  const u16* VTb = VT + (size_t)(b * 8 + h) * 192 * 2048;
  const float* ksqp = KSQ2 + bh * 2048;
  u16* sP = smem + 73728 + wave * 512;

  // ---- staging: 3 regions x 1536 16B-chunks, 3 chunks/thread/region ----
  u32 ofsK[3], ofsV[3];
#pragma unroll
  for (int s = 0; s < 3; ++s) {
    int g = tid + s * 512;
    {
      int j = g / 24, pp = g - j * 24;           // K: 24 chunks per 384B row
      int q = (pp & ~7) | ((pp ^ j) & 7);
      ofsK[s] = (u32)((((q >> 3) * 4096 + b * 2048 + j) * 1024) + 512 + h * 64 + (q & 7) * 8);
    }
    {
      int f = g >> 3, pp = g & 7;                // V: 8 chunks per 128B row
      int q = pp ^ (f & 7);
      ofsV[s] = (u32)(f * 2048 + q * 8);
    }
  }
  auto STAGE = [&](int bo) {
#pragma unroll
    for (int s = 0; s < 3; ++s) {
      int g8 = (tid + s * 512) * 8;
      gload16(QKVH + ofsK[s], smem + bo + g8);
      gload16(QKVL + ofsK[s], smem + bo + 12288 + g8);
      gload16(VTb + ofsV[s], smem + bo + 24576 + g8);
      ofsK[s] += 65536; ofsV[s] += 64;           // advance 64 j-rows
    }
  };

  STAGE(0);
  __syncthreads();      // vmcnt(0): tile 0 ready

  auto BODY = [&](int t, int bo) {
    float kq0 = ksqp[t * 64 + wj * 32 + la];
    float kq1 = ksqp[t * 64 + wj * 32 + 16 + la];
    if (t < 31) STAGE(bo ^ BUFU);

    // ---- QK^T (3-term bf16x2), wave's 16 rows x its 32-j half ----
    float4v S[2];
    S[0] = (float4v){0.f, 0.f, 0.f, 0.f};
    S[1] = (float4v){0.f, 0.f, 0.f, 0.f};
    __builtin_amdgcn_s_setprio(1);
#pragma unroll
    for (int kk = 0; kk < 6; ++kk) {
      int lc = kk * 4 + qa;
#pragma unroll
      for (int nf = 0; nf < 2; ++nf) {
        int jl = wj * 32 + nf * 16 + la;
        int phys = (lc & ~7) | ((lc ^ jl) & 7);
        int off = bo + jl * 192 + phys * 8;
        short8 kh = *(const short8*)(smem + off);
        short8 kl = *(const short8*)(smem + 12288 + off);
        S[nf] = mfma16(qh[kk], kh, S[nf]);
        S[nf] = mfma16(qh[kk], kl, S[nf]);
        S[nf] = mfma16(ql[kk], kh, S[nf]);
      }
    }
    __builtin_amdgcn_s_setprio(0);

    // ---- online softmax in log2 domain ----
    float Lh[2][4];
#pragma unroll
    for (int r = 0; r < 4; ++r) {
      Lh[0][r] = __builtin_fmaf(S[0][r], C2_F, -kq0);
      Lh[1][r] = __builtin_fmaf(S[1][r], C2_F, -kq1);
    }
    float lm[4];
#pragma unroll
    for (int r = 0; r < 4; ++r) lm[r] = fmaxf(Lh[0][r], Lh[1][r]);
    float worst = fmaxf(fmaxf(lm[0] - mr[0], lm[1] - mr[1]),
                        fmaxf(lm[2] - mr[2], lm[3] - mr[3]));
    float p0[4], p1[4];
    if (__all(worst <= THR_F)) {
#pragma unroll
      for (int r = 0; r < 4; ++r) {
        p0[r] = __builtin_exp2f(Lh[0][r] - mr[r]);
        p1[r] = __builtin_exp2f(Lh[1][r] - mr[r]);
        ssum[r] += p0[r] + p1[r];
      }
    } else {
#pragma unroll
      for (int r = 0; r < 4; ++r) {
        float rm = lm[r];
#pragma unroll
        for (int o = 1; o < 16; o <<= 1) rm = fmaxf(rm, __shfl_xor(rm, o));
        float mn = fmaxf(mr[r], rm);
        float alpha = __builtin_exp2f(mr[r] - mn);
        mr[r] = mn;
        p0[r] = __builtin_exp2f(Lh[0][r] - mn);
        p1[r] = __builtin_exp2f(Lh[1][r] - mn);
        ssum[r] = ssum[r] * alpha + p0[r] + p1[r];
#pragma unroll
        for (int nf2 = 0; nf2 < 12; ++nf2) O[nf2][r] *= alpha;
      }
    }

    // ---- P -> per-wave LDS via hw cvt_pk, read back in A-layout ----
#pragma unroll
    for (int r = 0; r < 4; ++r) {
      int i = qa * 4 + r;
      __hip_bfloat162 b2 = __float22bfloat162_rn(float2{p0[r], p1[r]});
      u32 pk; memcpy(&pk, &b2, 4);
      int sw = (i >> 1) & 3;
      sP[i * 32 + (((la >> 3) ^ sw) << 3) + (la & 7)] = (u16)pk;
      sP[i * 32 + ((((la >> 3) + 2) ^ sw) << 3) + (la & 7)] = (u16)(pk >> 16);
    }
    short8 pa = *(const short8*)(sP + la * 32 + ((qa ^ ((la >> 1) & 3)) << 3));

    // ---- PV over the wave's 32-j half ----
    __builtin_amdgcn_s_setprio(1);
#pragma unroll
    for (int nf = 0; nf < 12; ++nf) {
      int f = nf * 16 + la;
      int phys = (wj * 4 + qa) ^ (f & 7);
      int off = bo + 24576 + f * 64 + phys * 8;
      short8 vf = *(const short8*)(smem + off);
      O[nf] = mfma16(pa, vf, O[nf]);
    }
    __builtin_amdgcn_s_setprio(0);

    __syncthreads();   // vmcnt(0)+lgkm: next tile staged; buffers swap
  };

  for (int tt = 0; tt < 32; tt += 2) {
    BODY(tt, 0);
    BODY(tt + 1, BUFU);
  }

  // ---- epilogue: merge the two j-halves of each m-tile (in-block) ----
#pragma unroll
  for (int r = 0; r < 4; ++r) {
    float s = ssum[r];
#pragma unroll
    for (int o = 1; o < 16; o <<= 1) s += __shfl_xor(s, o);
    ssum[r] = s;
  }
  float* oex = (float*)smem;                     // [64 rows][stride 200] f32
  float* msx = (float*)(smem + 32768);           // [wm][wj][16][2] f32 (byte 65536)
  if (la == 0) {
#pragma unroll
    for (int r = 0; r < 4; ++r) {
      int row = qa * 4 + r;
      float* mp = msx + ((wm * 2 + wj) * 16 + row) * 2;
      mp[0] = mr[r];
      mp[1] = ssum[r];
    }
  }
  __syncthreads();
  float asc[4], inv[4];
#pragma unroll
  for (int r = 0; r < 4; ++r) {
    int row = qa * 4 + r;
    const float* mo = msx + ((wm * 2 + (1 - wj)) * 16 + row) * 2;
    float m_o = mo[0], s_o = mo[1];
    float ms = fmaxf(mr[r], m_o);
    float a_self = __builtin_exp2f(mr[r] - ms);
    float a_o = __builtin_exp2f(m_o - ms);
    asc[r] = a_self;
    inv[r] = 1.0f / (a_self * ssum[r] + a_o * s_o);
  }
  if (wj == 1) {
#pragma unroll
    for (int nf = 0; nf < 12; ++nf) {
      int f = nf * 16 + la;
#pragma unroll
      for (int r = 0; r < 4; ++r)
        oex[(wm * 16 + qa * 4 + r) * 200 + f] = O[nf][r] * asc[r];
    }
  }
  __syncthreads();
  if (wj == 0) {
#pragma unroll
    for (int nf = 0; nf < 12; ++nf) {
      int f = nf * 16 + la;
      int c = f >> 6, d = f & 63;
#pragma unroll
      for (int r = 0; r < 4; ++r) {
        int row = qa * 4 + r;
        float o = O[nf][r] * asc[r] + oex[(wm * 16 + row) * 200 + f];
        int ig = qb * 64 + wm * 16 + row;
        AO[(c * 4096 + b * 2048 + ig) * 512 + h * 64 + d] = f2bf(o * inv[r]);
      }
    }
  }
}

// ================= kernel 5: final projection GEMM ========================
__global__ __launch_bounds__(256) void out_gemm(
    const u16* __restrict__ AO, const u16* __restrict__ WOH, float* __restrict__ OUT) {
  __shared__ u16 smem[8192];
  int m0 = blockIdx.x * 128, n0 = blockIdx.y * 128;
  int tid = threadIdx.x, lane = tid & 63, wave = tid >> 6;
  int la = lane & 15, qa = lane >> 4;
  int wm = wave >> 1, wn = wave & 1;

  float4v acc[4][4];
#pragma unroll
  for (int i = 0; i < 4; ++i)
#pragma unroll
    for (int j = 0; j < 4; ++j) acc[i][j] = (float4v){0.f, 0.f, 0.f, 0.f};

  for (int k0 = 0; k0 < 512; k0 += 32) {
    __syncthreads();
#pragma unroll
    for (int it = 0; it < 4; ++it) {
      int cb = it * 256 + wave * 64;
      int n = cb + lane;
      int region = n >> 9;
      int nn = n & 511;
      int row = nn >> 2, p = nn & 3;
      int q = p ^ ((row >> 1) & 3);
      const u16* src = (region == 0) ? AO + (m0 + row) * 512 + k0 + q * 8
                                     : WOH + (n0 + row) * 512 + k0 + q * 8;
      gload16(src, smem + cb * 8);
    }
    __syncthreads();

    short8 ah[4];
#pragma unroll
    for (int mi = 0; mi < 4; ++mi) {
      int row = wm * 64 + mi * 16 + la;
      int off = row * 32 + ((qa ^ ((row >> 1) & 3)) * 8);
      ah[mi] = *(const short8*)(smem + off);
    }
#pragma unroll
    for (int ni = 0; ni < 4; ++ni) {
      int row = wn * 64 + ni * 16 + la;
      int off = row * 32 + ((qa ^ ((row >> 1) & 3)) * 8);
      short8 bhf = *(const short8*)(smem + 4096 + off);
#pragma unroll
      for (int mi = 0; mi < 4; ++mi) acc[mi][ni] = mfma16(ah[mi], bhf, acc[mi][ni]);
    }
  }

#pragma unroll
  for (int mi = 0; mi < 4; ++mi)
#pragma unroll
    for (int ni = 0; ni < 4; ++ni) {
      int n = n0 + wn * 64 + ni * 16 + la;
      int mbase = m0 + wm * 64 + mi * 16 + qa * 4;
#pragma unroll
      for (int r = 0; r < 4; ++r) {
        int m = mbase + r;
        int c = m >> 12, bn = m & 4095;
        OUT[bn * 768 + n * 3 + c] = acc[mi][ni][r];
      }
    }
}

// ================= launch =================================================
extern "C" void kernel_launch(void* const* d_in, const int* in_sizes, int n_in,
                              void* d_out, int out_size, void* d_ws, size_t ws_size,
                              hipStream_t stream) {
  const float* x    = (const float*)d_in[0];
  const float* wq   = (const float*)d_in[2];
  const float* wkv  = (const float*)d_in[3];
  const float* wout = (const float*)d_in[4];

  char* ws = (char*)d_ws;
  u16*  XH   = (u16*)(ws + OFF_XH);
  u16*  XL   = (u16*)(ws + OFF_XL);
  u16*  AO1  = (u16*)(ws + OFF_AO1);
  u16*  WH   = (u16*)(ws + OFF_WH);
  u16*  WL   = (u16*)(ws + OFF_WL);
  u16*  WOH  = (u16*)(ws + OFF_WOH);
  u16*  QKVH = (u16*)(ws + OFF_QKVH);
  u16*  QKVL = (u16*)(ws + OFF_QKVL);
  u16*  VT   = (u16*)(ws + OFF_VT);
  float* KSQ2 = (float*)(ws + OFF_KSQ);

  prep_kernel<<<6144, 256, 0, stream>>>(x, wq, wkv, wout, XH, XL, WH, WL, WOH);
  qkv_gemm<<<dim3(96, 12), 256, 0, stream>>>(XH, XL, WH, WL, QKVH, QKVL, VT);
  ksq_kernel<<<4096, 512, 0, stream>>>(QKVH, QKVL, KSQ2);
  attn_kernel<<<512, 512, 0, stream>>>(QKVH, QKVL, VT, KSQ2, AO1);
  out_gemm<<<dim3(96, 2), 256, 0, stream>>>(AO1, WOH, (float*)d_out);
}